// Round 1
// baseline (33.510 us; speedup 1.0000x reference)
//
#include <hip/hip_runtime.h>

// CountVectorizer: hash 4x4-byte packed word groups, look up in collision
// table, scatter-add per-document counts, scaled.
//
// Shapes (fixed by the reference harness):
//   documents       [N, W, 4] int32   N = 1,048,576, W = 4
//   doc_ids         [N]       int32
//   batch_size      scalar    (512)
//   hash_table      [V, C, W] int32   V = 32000, C = 2
//   feature_indices [V, C]    int32
//   powers_of_two   [4]       int32
//   scale           [1]       float32
//   out             [BATCH, V] float32

constexpr int V_VOCAB = 32000;   // compile-time so % becomes magic-mul
constexpr int C_COLL  = 2;
constexpr int W_GROUPS = 4;

__global__ __launch_bounds__(256)
void cv_count_kernel(const int4* __restrict__ docs,      // [N, W] int4 (4 bytes/group)
                     const int*  __restrict__ doc_ids,   // [N]
                     const int*  __restrict__ hash_table,// [V, C, W]
                     const int2* __restrict__ feat_idx,  // [V] int2 (C=2)
                     const int*  __restrict__ powers,    // [4]
                     const float* __restrict__ scale_p,  // [1]
                     float* __restrict__ out,            // [BATCH, V]
                     int N)
{
    int tid = blockIdx.x * blockDim.x + threadIdx.x;
    if (tid >= N) return;

    const int p0 = powers[0], p1 = powers[1], p2 = powers[2], p3 = powers[3];
    const float scale = scale_p[0];

    // Load the word's 16 bytes-as-int32 (64 B) as 4x int4, pack each group.
    int packed[W_GROUPS];
#pragma unroll
    for (int w = 0; w < W_GROUPS; ++w) {
        int4 b = docs[(size_t)tid * W_GROUPS + w];
        packed[w] = b.x * p0 + b.y * p1 + b.z * p2 + b.w * p3;
    }

    // h ^= pu * c1 * c2  ==  h ^= pu * (c1*c2 mod 2^32)
    const unsigned K = 3432918353u * 461845907u;  // constant-folded
    unsigned h = 0;
#pragma unroll
    for (int w = 0; w < W_GROUPS; ++w) h ^= (unsigned)packed[w] * K;
    unsigned idx = h % (unsigned)V_VOCAB;

    // Gather both collision slots (32 B) + feature ids (8 B); tables are
    // L2/L3-resident (1 MB + 256 KB).
    const int4* ht = (const int4*)(hash_table + (size_t)idx * (C_COLL * W_GROUPS));
    int4 e0 = ht[0];
    int4 e1 = ht[1];
    int2 fi = feat_idx[idx];

    bool m0 = (e0.x == packed[0]) & (e0.y == packed[1]) &
              (e0.z == packed[2]) & (e0.w == packed[3]);
    bool m1 = (e1.x == packed[0]) & (e1.y == packed[1]) &
              (e1.z == packed[2]) & (e1.w == packed[3]);
    int feat = (m0 ? fi.x : 0) + (m1 ? fi.y : 0);   // 0 = miss

    if (feat > 0) {
        int doc = doc_ids[tid];
        // Fuse the final `* scale` into the scatter: count*scale == sum of scale.
        atomicAdd(out + (size_t)doc * V_VOCAB + (feat - 1), scale);
    }
}

extern "C" void kernel_launch(void* const* d_in, const int* in_sizes, int n_in,
                              void* d_out, int out_size, void* d_ws, size_t ws_size,
                              hipStream_t stream) {
    const int4* docs       = (const int4*)d_in[0];
    const int*  doc_ids    = (const int*) d_in[1];
    // d_in[2] = batch_size scalar (unused on device; out_size/V gives BATCH)
    const int*  hash_table = (const int*) d_in[3];
    const int2* feat_idx   = (const int2*)d_in[4];
    const int*  powers     = (const int*) d_in[5];
    const float* scale     = (const float*)d_in[6];
    float* out = (float*)d_out;

    const int N = in_sizes[1];  // one entry per word

    // Output must be zeroed every call (harness poisons once, never restores).
    hipMemsetAsync(d_out, 0, (size_t)out_size * sizeof(float), stream);

    const int block = 256;
    const int grid = (N + block - 1) / block;
    cv_count_kernel<<<grid, block, 0, stream>>>(docs, doc_ids, hash_table,
                                                feat_idx, powers, scale, out, N);
}